// Round 6
// baseline (1387.906 us; speedup 1.0000x reference)
//
#include <hip/hip_runtime.h>

typedef unsigned short u16;
typedef __attribute__((ext_vector_type(8))) short bf16x8;
typedef __attribute__((ext_vector_type(4))) float f32x4;

#define PITCH 40   // small-conv kernel LDS pitch (shorts)

__device__ __forceinline__ u16 f2bf(float f) {
  union { float f; unsigned u; } v; v.f = f;
  unsigned r = v.u + 0x7fffu + ((v.u >> 16) & 1u);
  return (u16)(r >> 16);
}
__device__ __forceinline__ float bf2f(u16 h) {
  union { unsigned u; float f; } v; v.u = ((unsigned)h) << 16;
  return v.f;
}
__device__ __forceinline__ float4 load4bf(const u16* p) {
  ushort4 h = *(const ushort4*)p;
  return make_float4(bf2f(h.x), bf2f(h.y), bf2f(h.z), bf2f(h.w));
}
// async global->LDS, 16B per lane; LDS dest = wave-uniform base + lane*16
__device__ __forceinline__ void gll16(const u16* g, u16* l) {
  __builtin_amdgcn_global_load_lds(
      (const __attribute__((address_space(1))) unsigned int*)g,
      (__attribute__((address_space(3))) unsigned int*)l, 16, 0, 0);
}

// ---------------- transpose (l,c,d,h,w) -> token-major [n=(l,d,h,w), c] fp32 ----------------
__global__ __launch_bounds__(256) void k_transpose_in(const float* __restrict__ x,
                                                      float* __restrict__ xt) {
  int idx = blockIdx.x * 256 + threadIdx.x;
  int c = idx & 127;
  int n = idx >> 7;
  int l = n >> 12;
  int s = n & 4095;
  xt[idx] = x[((l * 128 + c) << 12) + s];
}

__global__ __launch_bounds__(256) void k_transpose_out(const float* __restrict__ xt,
                                                       float* __restrict__ out) {
  int idx = blockIdx.x * 256 + threadIdx.x;
  int s = idx & 4095;
  int c = (idx >> 12) & 127;
  int l = idx >> 19;
  out[idx] = xt[(((l << 12) | s) << 7) + c];
}

__global__ __launch_bounds__(128) void k_zeropage(u16* __restrict__ zp) {
  zp[threadIdx.x] = 0;
}

// ---------------- layernorm fp32 in -> bf16 out, one wave per row ----------------
__global__ __launch_bounds__(256) void k_ln_f2b(const float* __restrict__ X,
                                                const float* __restrict__ g,
                                                const float* __restrict__ b,
                                                u16* __restrict__ Y, int M) {
  int n = blockIdx.x * 4 + (threadIdx.x >> 6);
  if (n >= M) return;
  int lane = threadIdx.x & 63;
  const float* row = X + (long)n * 128;
  float2 v = *(const float2*)(row + lane * 2);
  float s = v.x + v.y;
#pragma unroll
  for (int o = 32; o > 0; o >>= 1) s += __shfl_xor(s, o);
  float mu = s * (1.0f / 128.0f);
  float dx = v.x - mu, dy = v.y - mu;
  float q = dx * dx + dy * dy;
#pragma unroll
  for (int o = 32; o > 0; o >>= 1) q += __shfl_xor(q, o);
  float rs = rsqrtf(q * (1.0f / 128.0f) + 1e-5f);
  float2 gv = *(const float2*)(g + lane * 2);
  float2 bv = *(const float2*)(b + lane * 2);
  ushort2 o2;
  o2.x = f2bf(dx * rs * gv.x + bv.x);
  o2.y = f2bf(dy * rs * gv.y + bv.y);
  *(ushort2*)(Y + (long)n * 128 + lane * 2) = o2;
}

// ---------------- weight repack: W[oc][ic][tap] fp32 -> Wb[tap][oc][ic] bf16 ----------------
__global__ __launch_bounds__(256) void k_repack_bf(const float* __restrict__ W,
                                                   u16* __restrict__ Wb,
                                                   int lgOC, int lgIC, int NT, long tot) {
  long idx = (long)blockIdx.x * 256 + threadIdx.x;
  if (idx >= tot) return;
  int ic = (int)(idx & ((1 << lgIC) - 1));
  long r = idx >> lgIC;
  int oc = (int)(r & ((1 << lgOC) - 1));
  int t = (int)(r >> lgOC);
  Wb[idx] = f2bf(W[(((long)oc << lgIC) | ic) * NT + t]);
}

// ---------------- small conv-as-gather-GEMM (64 x 64 tile) for small M ----------------
// flags: 1=ACC into fp32 Y, 2=RELU, 4=bf16 out (else fp32 out)
__global__ __launch_bounds__(256) void k_conv_mfma(
    const u16* __restrict__ X, const u16* __restrict__ W3,
    const float* __restrict__ bias, void* __restrict__ Yv,
    int M, int IC, int OC, int mode, int NT,
    int lgWo, int lgHo, int lgDo,
    int lgWi, int lgHi, int lgDi,
    int Li, int Di, int Hi, int Wi,
    int sL, int sD, int sH, int sW, int flags) {
  __shared__ u16 As[64 * PITCH];
  __shared__ u16 Bs[64 * PITCH];
  int tid = threadIdx.x;
  int wave = tid >> 6, lane = tid & 63;
  int quad = lane >> 4, l15 = lane & 15;
  int m0 = blockIdx.x * 64;
  int oc0 = blockIdx.y * 64;

  int srl = tid >> 2;
  int sao = (tid & 3) * 8;
  int sboc = tid >> 2, sbo = (tid & 3) * 8;

  int sm = m0 + srl;
  bool mv = sm < M;
  int w = sm & ((1 << lgWo) - 1);
  int h = (sm >> lgWo) & ((1 << lgHo) - 1);
  int d = (sm >> (lgWo + lgHo)) & ((1 << lgDo) - 1);
  int l = sm >> (lgWo + lgHo + lgDo);

  int c0 = 0, c1 = 0, c2 = 0, c3 = 0;
  auto comp_nb = [&]() -> long {
    if (!mv) return -1;
    int li, di, hi, wi; bool ok;
    if (mode == 0) {
      int dl = c0 - 1;
      int ll = (l & 1) + dl;
      ok = (ll >= 0 && ll < 2);
      li = l + dl; di = d; hi = h; wi = w;
    } else if (mode == 1) {
      li = l * sL; di = d * sD + c2 - 1; hi = h * sH + c1 - 1; wi = w * sW + c0 - 1;
      ok = ((unsigned)di < (unsigned)Di) && ((unsigned)hi < (unsigned)Hi) &&
           ((unsigned)wi < (unsigned)Wi);
    } else {
      li = l + c3 - 1; di = d + c2 - 1; hi = h + c1 - 1; wi = w + c0 - 1;
      ok = ((unsigned)li < (unsigned)Li) && ((unsigned)di < (unsigned)Di) &&
           ((unsigned)hi < (unsigned)Hi) && ((unsigned)wi < (unsigned)Wi);
    }
    if (!ok) return -1;
    return ((((long)((li << lgDi) + di) << lgHi) + hi) << lgWi) + wi;
  };

  long nb = comp_nb();
  const u16* wt = W3 + (long)(oc0 + sboc) * IC + sbo;
  long wstep = (long)OC * IC;
  int kmask = (IC >> 5) - 1;
  int total = NT * (IC >> 5);

  const bf16x8 Z = {0, 0, 0, 0, 0, 0, 0, 0};
  bf16x8 ra0 = Z, rb;
  if (nb >= 0) ra0 = *(const bf16x8*)(X + nb * IC + sao);
  rb = *(const bf16x8*)wt;

  f32x4 acc[4];
#pragma unroll
  for (int j = 0; j < 4; ++j) acc[j] = {0.f, 0.f, 0.f, 0.f};

  int wrow = wave * 16;

  for (int ks = 0; ks < total; ++ks) {
    __syncthreads();
    *(bf16x8*)&As[srl * PITCH + sao] = ra0;
    *(bf16x8*)&Bs[sboc * PITCH + sbo] = rb;
    __syncthreads();
    int ksn = ks + 1;
    if (ksn < total) {
      int k0n = (ksn & kmask) << 5;
      if ((ksn & kmask) == 0) {
        wt += wstep;
        if (++c0 == 3) { c0 = 0; if (++c1 == 3) { c1 = 0; if (++c2 == 3) { c2 = 0; ++c3; } } }
        nb = comp_nb();
      }
      ra0 = Z;
      if (nb >= 0) ra0 = *(const bf16x8*)(X + nb * IC + k0n + sao);
      rb = *(const bf16x8*)(wt + k0n);
    }
    bf16x8 a0 = *(const bf16x8*)&As[(wrow + l15) * PITCH + quad * 8];
#pragma unroll
    for (int j = 0; j < 4; ++j) {
      bf16x8 b = *(const bf16x8*)&Bs[(j * 16 + l15) * PITCH + quad * 8];
      acc[j] = __builtin_amdgcn_mfma_f32_16x16x32_bf16(a0, b, acc[j], 0, 0, 0);
    }
  }

  int col = oc0 + l15;
#pragma unroll
  for (int j = 0; j < 4; ++j) {
    float bj = bias[col + j * 16];
    int rbase = m0 + wrow + quad * 4;
#pragma unroll
    for (int r = 0; r < 4; ++r) {
      int row = rbase + r;
      if (row >= M) continue;
      float v = acc[j][r] + bj;
      if (flags & 2) v = fmaxf(v, 0.f);
      long off = (long)row * OC + col + j * 16;
      if (flags & 4) ((u16*)Yv)[off] = f2bf(v);
      else if (flags & 1) ((float*)Yv)[off] += v;
      else ((float*)Yv)[off] = v;
    }
  }
}

// ---------------- big conv-GEMM: 128x128 tile, double-buffered global_load_lds ----------------
// LDS: 2 buffers of [row][32 shorts], chunk swizzle: physical = (logical + (row>>1)) & 3.
// Raw s_barrier + explicit vmcnt(4): prefetch for tile t+1 stays in flight across the
// barrier; the wait is one iteration deep (never vmcnt(0) in steady state).
// NSPLIT>1 -> raw fp32 partials into SP. flags (NSPLIT==1): 1=ACC fp32, 2=RELU, 4=bf16 out
__global__ __launch_bounds__(256) void k_conv_gl(
    const u16* __restrict__ X, const u16* __restrict__ W3,
    const float* __restrict__ bias, void* __restrict__ Yv, float* __restrict__ SP,
    const u16* __restrict__ ZP,
    int M, int IC, int OC, int mode, int NT, int NSPLIT,
    int lgWo, int lgHo, int lgDo,
    int lgWi, int lgHi, int lgDi,
    int Li, int Di, int Hi, int Wi,
    int sL, int sD, int sH, int sW, int flags) {
  __shared__ __align__(16) u16 As[2][128 * 32];
  __shared__ __align__(16) u16 Bs[2][128 * 32];
  int tid = threadIdx.x;
  int wave = tid >> 6, lane = tid & 63;
  int quad = lane >> 4, l15 = lane & 15;
  int m0 = blockIdx.x * 128, oc0 = blockIdx.y * 128;
  int mi = wave & 1, ni = wave >> 1;

  // staging: this thread covers rows r0 and r1 (= r0+16), chunk pc, of both A and B
  int pc = lane & 3;
  int r0 = wave * 32 + (lane >> 2);
  int r1 = r0 + 16;
  int lcA0 = (pc - (r0 >> 1)) & 3;
  int lcA1 = (pc - (r1 >> 1)) & 3;

  // token decode for A rows
  int sm0 = m0 + r0, sm1 = m0 + r1;
  bool v0 = sm0 < M, v1 = sm1 < M;
  int w0 = sm0 & ((1 << lgWo) - 1), h0 = (sm0 >> lgWo) & ((1 << lgHo) - 1);
  int d0 = (sm0 >> (lgWo + lgHo)) & ((1 << lgDo) - 1), l0 = sm0 >> (lgWo + lgHo + lgDo);
  int w1 = sm1 & ((1 << lgWo) - 1), h1 = (sm1 >> lgWo) & ((1 << lgHo) - 1);
  int d1 = (sm1 >> (lgWo + lgHo)) & ((1 << lgDo) - 1), l1 = sm1 >> (lgWo + lgHo + lgDo);

  int tap_per = (NT + NSPLIT - 1) / NSPLIT;
  int t0 = blockIdx.z * tap_per;
  int t1 = min(NT, t0 + tap_per);
  int kc = IC >> 5;
  int total = (t1 - t0) * kc;

  int c0 = t0 % 3, c1 = (t0 / 3) % 3, c2 = (t0 / 9) % 3, c3 = t0 / 27;
  auto comp_nb = [&](bool mv, int w, int h, int d, int l) -> long {
    if (!mv) return -1;
    int li, di, hi, wi; bool ok;
    if (mode == 0) {
      int dl = c0 - 1;
      int ll = (l & 1) + dl;
      ok = (ll >= 0 && ll < 2);
      li = l + dl; di = d; hi = h; wi = w;
    } else if (mode == 1) {
      li = l * sL; di = d * sD + c2 - 1; hi = h * sH + c1 - 1; wi = w * sW + c0 - 1;
      ok = ((unsigned)di < (unsigned)Di) && ((unsigned)hi < (unsigned)Hi) &&
           ((unsigned)wi < (unsigned)Wi);
    } else {
      li = l + c3 - 1; di = d + c2 - 1; hi = h + c1 - 1; wi = w + c0 - 1;
      ok = ((unsigned)li < (unsigned)Li) && ((unsigned)di < (unsigned)Di) &&
           ((unsigned)hi < (unsigned)Hi) && ((unsigned)wi < (unsigned)Wi);
    }
    if (!ok) return -1;
    return ((((long)((li << lgDi) + di) << lgHi) + hi) << lgWi) + wi;
  };

  long nbA0 = comp_nb(v0, w0, h0, d0, l0);
  long nbA1 = comp_nb(v1, w1, h1, d1, l1);
  long wstep = (long)OC * IC;
  const u16* wB0 = W3 + ((long)t0 * OC + oc0 + r0) * IC + lcA0 * 8;
  const u16* wB1 = W3 + ((long)t0 * OC + oc0 + r1) * IC + lcA1 * 8;

  int kk = 0;  // issue-position k-chunk within IC
  auto issue = [&](int b) {
    int k0i = kk << 5;
    const u16* a0 = (nbA0 >= 0) ? X + nbA0 * IC + k0i + lcA0 * 8 : ZP;
    const u16* a1 = (nbA1 >= 0) ? X + nbA1 * IC + k0i + lcA1 * 8 : ZP;
    u16* lA = &As[b][wave * 512];   // wave covers 16 rows (512 shorts) per issue
    u16* lB = &Bs[b][wave * 512];
    // NOTE: As rows wave*32.. : base offset = wave*32*32 = wave*1024 shorts total,
    // issued as two 16-row halves:
    gll16(a0, &As[b][wave * 1024]);
    gll16(a1, &As[b][wave * 1024 + 512]);
    gll16(wB0 + k0i, &Bs[b][wave * 1024]);
    gll16(wB1 + k0i, &Bs[b][wave * 1024 + 512]);
    (void)lA; (void)lB;
  };
  auto advance = [&]() {
    if (++kk == kc) {
      kk = 0;
      if (++c0 == 3) { c0 = 0; if (++c1 == 3) { c1 = 0; if (++c2 == 3) { c2 = 0; ++c3; } } }
      nbA0 = comp_nb(v0, w0, h0, d0, l0);
      nbA1 = comp_nb(v1, w1, h1, d1, l1);
      wB0 += wstep;
      wB1 += wstep;
    }
  };

  f32x4 acc[4][4];
#pragma unroll
  for (int i = 0; i < 4; ++i)
#pragma unroll
    for (int j = 0; j < 4; ++j) acc[i][j] = {0.f, 0.f, 0.f, 0.f};

  issue(0);
  advance();

  for (int ks = 0; ks < total; ++ks) {
    int cur = ks & 1;
    if (ks + 1 < total) {
      issue((ks + 1) & 1);
      advance();
      asm volatile("s_waitcnt vmcnt(4)\n\ts_barrier" ::: "memory");
    } else {
      asm volatile("s_waitcnt vmcnt(0)\n\ts_barrier" ::: "memory");
    }
    bf16x8 af[4], bf[4];
#pragma unroll
    for (int i = 0; i < 4; ++i) {
      int row = mi * 64 + i * 16 + l15;
      int pa = (quad + (row >> 1)) & 3;
      af[i] = *(const bf16x8*)&As[cur][row * 32 + pa * 8];
    }
#pragma unroll
    for (int j = 0; j < 4; ++j) {
      int row = ni * 64 + j * 16 + l15;
      int pb = (quad + (row >> 1)) & 3;
      bf[j] = *(const bf16x8*)&Bs[cur][row * 32 + pb * 8];
    }
#pragma unroll
    for (int i = 0; i < 4; ++i)
#pragma unroll
      for (int j = 0; j < 4; ++j)
        acc[i][j] = __builtin_amdgcn_mfma_f32_16x16x32_bf16(af[i], bf[j], acc[i][j], 0, 0, 0);
    // guard buffer reuse: next iteration's issue overwrites buf[cur]
    asm volatile("s_waitcnt lgkmcnt(0)\n\ts_barrier" ::: "memory");
  }

  // epilogue: C/D layout col=l15, row=quad*4+r
  if (NSPLIT > 1) {
    float* out = SP + (long)blockIdx.z * M * OC;
#pragma unroll
    for (int j = 0; j < 4; ++j) {
      int c = oc0 + ni * 64 + j * 16 + l15;
#pragma unroll
      for (int i = 0; i < 4; ++i) {
        int rbase = m0 + mi * 64 + i * 16 + quad * 4;
#pragma unroll
        for (int r = 0; r < 4; ++r) {
          int row = rbase + r;
          if (row < M) out[(long)row * OC + c] = acc[i][j][r];
        }
      }
    }
  } else {
#pragma unroll
    for (int j = 0; j < 4; ++j) {
      int c = oc0 + ni * 64 + j * 16 + l15;
      float bj = bias[c];
#pragma unroll
      for (int i = 0; i < 4; ++i) {
        int rbase = m0 + mi * 64 + i * 16 + quad * 4;
#pragma unroll
        for (int r = 0; r < 4; ++r) {
          int row = rbase + r;
          if (row >= M) continue;
          float v = acc[i][j][r] + bj;
          if (flags & 2) v = fmaxf(v, 0.f);
          long off = (long)row * OC + c;
          if (flags & 4) ((u16*)Yv)[off] = f2bf(v);
          else if (flags & 1) ((float*)Yv)[off] += v;
          else ((float*)Yv)[off] = v;
        }
      }
    }
  }
}

// ---------------- combine split-K partials: out = (sum_s SP[s]) + bias ----------------
__global__ __launch_bounds__(256) void k_combine(const float* __restrict__ SP,
                                                 const float* __restrict__ bias,
                                                 void* __restrict__ out,
                                                 long MOC, int lgOC, int nsplit, int flags) {
  long idx = (long)blockIdx.x * 256 + threadIdx.x;
  if (idx >= MOC) return;
  float v = bias[idx & ((1 << lgOC) - 1)];
  for (int s = 0; s < nsplit; ++s) v += SP[s * MOC + idx];
  if (flags & 2) v = fmaxf(v, 0.f);
  if (flags & 4) ((u16*)out)[idx] = f2bf(v);
  else if (flags & 1) ((float*)out)[idx] += v;
  else ((float*)out)[idx] = v;
}

// ---------------- TLG windowed cross attention: 8q x 8k per (window, head), bf16 ----------------
__global__ __launch_bounds__(256) void k_tlg_attn(const u16* __restrict__ Q,
                                                  const u16* __restrict__ K,
                                                  const u16* __restrict__ V,
                                                  u16* __restrict__ Y) {
  int gw = blockIdx.x * 4 + (threadIdx.x >> 6);
  int lane = threadIdx.x & 63;
  int head = gw & 7;
  int win = gw >> 3;
  int wB = win & 7, hB = (win >> 3) & 7, dB = (win >> 6) & 7, l = win >> 9;
  int i = lane >> 3, j = lane & 7;
  int nq = (l << 12) | ((dB * 2 + (i >> 2)) << 8) | ((hB * 2 + ((i >> 1) & 1)) << 4) |
           (wB * 2 + (i & 1));
  int lk = l ^ 2;
  int nk = (lk << 12) | ((dB * 2 + (j >> 2)) << 8) | ((hB * 2 + ((j >> 1) & 1)) << 4) |
           (wB * 2 + (j & 1));
  int hoff = head * 16;
  const u16* qp = Q + (long)nq * 128 + hoff;
  const u16* kp = K + (long)nk * 128 + hoff;
  float s = 0.f;
#pragma unroll
  for (int t = 0; t < 16; t += 4) {
    float4 a = load4bf(qp + t);
    float4 b = load4bf(kp + t);
    s += a.x * b.x + a.y * b.y + a.z * b.z + a.w * b.w;
  }
  s *= 0.25f;
  float mx = s;
#pragma unroll
  for (int o = 1; o < 8; o <<= 1) mx = fmaxf(mx, __shfl_xor(mx, o));
  float e = __expf(s - mx);
  float sum = e;
#pragma unroll
  for (int o = 1; o < 8; o <<= 1) sum += __shfl_xor(sum, o);
  float p = e / sum;
  const u16* vp = V + (long)nk * 128 + hoff;
  float y[16];
#pragma unroll
  for (int t = 0; t < 16; t += 4) {
    float4 vv = load4bf(vp + t);
    y[t] = p * vv.x; y[t + 1] = p * vv.y; y[t + 2] = p * vv.z; y[t + 3] = p * vv.w;
  }
#pragma unroll
  for (int o = 1; o < 8; o <<= 1) {
#pragma unroll
    for (int t = 0; t < 16; ++t) y[t] += __shfl_xor(y[t], o);
  }
  if (j == 0) {
    u16* yp = Y + (long)nq * 128 + hoff;
    u16 tmp[16];
#pragma unroll
    for (int t = 0; t < 16; ++t) tmp[t] = f2bf(y[t]);
    *(uint4*)(yp) = *(uint4*)tmp;
    *(uint4*)(yp + 8) = *(uint4*)(tmp + 8);
  }
}

// ---------------- SLG K/V repack for flash attn ----------------
__global__ __launch_bounds__(256) void k_pack_kh(const u16* __restrict__ Kin,
                                                 u16* __restrict__ Kh) {
  int idx = blockIdx.x * 256 + threadIdx.x;
  if (idx >= 8 * 1032 * 16) return;
  int d = idx & 15;
  int r = idx >> 4;
  int k = r % 1032, h = r / 1032;
  Kh[idx] = Kin[k * 128 + h * 16 + d];
}
__global__ __launch_bounds__(256) void k_pack_vt(const u16* __restrict__ Vin,
                                                 u16* __restrict__ Vt) {
  int idx = blockIdx.x * 256 + threadIdx.x;
  if (idx >= 8 * 16 * 1032) return;
  int k = idx % 1032;
  int r = idx / 1032;
  int d = r & 15, h = r >> 4;
  Vt[idx] = Vin[k * 128 + h * 16 + d];
}

// ---------------- SLG MFMA flash attention ----------------
__global__ __launch_bounds__(256) void k_slg_flash(const u16* __restrict__ Q,
                                                   const u16* __restrict__ Kh,
                                                   const u16* __restrict__ Vt,
                                                   u16* __restrict__ Y) {
  constexpr int NK = 1032;
  constexpr int NTILE = 17;
  __shared__ __align__(16) u16 Ks[64 * 24];
  __shared__ __align__(16) u16 Vs[16 * 72];
  __shared__ __align__(16) u16 Ps[4][16 * 72];
  int tid = threadIdx.x;
  int wave = tid >> 6, lane = tid & 63;
  int quad = lane >> 4, l15 = lane & 15;
  int h = blockIdx.x & 7;
  int q0 = (blockIdx.x >> 3) * 64 + wave * 16;

  const bf16x8 Zb = {0, 0, 0, 0, 0, 0, 0, 0};
  bf16x8 qf = Zb;
  if (quad < 2) qf = *(const bf16x8*)(Q + (long)(q0 + l15) * 128 + h * 16 + quad * 8);

  const u16* Kbase = Kh + (long)h * NK * 16;
  const u16* Vbase = Vt + (long)h * 16 * NK;

  float mrow[4], lrow[4];
  f32x4 oacc = {0.f, 0.f, 0.f, 0.f};
#pragma unroll
  for (int r = 0; r < 4; ++r) { mrow[r] = -1e30f; lrow[r] = 0.f; }

  int skey = tid >> 2, sch = (tid & 3) * 4;
  int svd = tid >> 4, svc = (tid & 15) * 4;

  for (int t = 0; t < NTILE; ++t) {
    int k0 = t * 64;
    __syncthreads();
    {
      short4 v = {0, 0, 0, 0};
      int key = k0 + skey;
      if (key < NK) v = *(const short4*)(Kbase + key * 16 + sch);
      *(short4*)&Ks[skey * 24 + sch] = v;
    }
    {
      short4 v = {0, 0, 0, 0};
      int colb = k0 + svc;
      if (colb < NK) v = *(const short4*)(Vbase + svd * NK + colb);
      *(short4*)&Vs[svd * 72 + svc] = v;
    }
    __syncthreads();

    f32x4 s[4];
#pragma unroll
    for (int sub = 0; sub < 4; ++sub) {
      bf16x8 b = Zb;
      if (quad < 2) b = *(const bf16x8*)&Ks[(sub * 16 + l15) * 24 + quad * 8];
      f32x4 zero = {0.f, 0.f, 0.f, 0.f};
      s[sub] = __builtin_amdgcn_mfma_f32_16x16x32_bf16(qf, b, zero, 0, 0, 0);
    }
    float pv[4][4];
    float tmax[4] = {-1e30f, -1e30f, -1e30f, -1e30f};
#pragma unroll
    for (int sub = 0; sub < 4; ++sub) {
      int key = k0 + sub * 16 + l15;
      bool valid = key < NK;
#pragma unroll
      for (int r = 0; r < 4; ++r) {
        float sv = valid ? s[sub][r] * 0.25f : -1e30f;
        pv[sub][r] = sv;
        tmax[r] = fmaxf(tmax[r], sv);
      }
    }
#pragma unroll
    for (int o = 1; o < 16; o <<= 1)
#pragma unroll
      for (int r = 0; r < 4; ++r) tmax[r] = fmaxf(tmax[r], __shfl_xor(tmax[r], o));

    float al[4], tsum[4] = {0.f, 0.f, 0.f, 0.f};
#pragma unroll
    for (int r = 0; r < 4; ++r) {
      float mn = fmaxf(mrow[r], tmax[r]);
      al[r] = __expf(mrow[r] - mn);
      mrow[r] = mn;
    }
#pragma unroll
    for (int sub = 0; sub < 4; ++sub)
#pragma unroll
      for (int r = 0; r < 4; ++r) {
        float pe = __expf(pv[sub][r] - mrow[r]);
        tsum[r] += pe;
        Ps[wave][(quad * 4 + r) * 72 + sub * 16 + l15] = f2bf(pe);
      }
#pragma unroll
    for (int o = 1; o < 16; o <<= 1)
#pragma unroll
      for (int r = 0; r < 4; ++r) tsum[r] += __shfl_xor(tsum[r], o);
#pragma unroll
    for (int r = 0; r < 4; ++r) {
      lrow[r] = lrow[r] * al[r] + tsum[r];
      oacc[r] *= al[r];
    }
    bf16x8 pa0 = *(const bf16x8*)&Ps[wave][l15 * 72 + quad * 8];
    bf16x8 pa1 = *(const bf16x8*)&Ps[wave][l15 * 72 + 32 + quad * 8];
    bf16x8 vb0 = *(const bf16x8*)&Vs[l15 * 72 + quad * 8];
    bf16x8 vb1 = *(const bf16x8*)&Vs[l15 * 72 + 32 + quad * 8];
    oacc = __builtin_amdgcn_mfma_f32_16x16x32_bf16(pa0, vb0, oacc, 0, 0, 0);
    oacc = __builtin_amdgcn_mfma_f32_16x16x32_bf16(pa1, vb1, oacc, 0, 0, 0);
  }

#pragma unroll
  for (int r = 0; r < 4; ++r) {
    float inv = 1.0f / lrow[r];
    Y[(long)(q0 + quad * 4 + r) * 128 + h * 16 + l15] = f2bf(oacc[r] * inv);
  }
}

static inline int ilg(int v) { int r = 0; while ((1 << r) < v) ++r; return r; }

extern "C" void kernel_launch(void* const* d_in, const int* in_sizes, int n_in,
                              void* d_out, int out_size, void* d_ws, size_t ws_size,
                              hipStream_t stream) {
  (void)in_sizes; (void)n_in; (void)out_size; (void)ws_size;
  const float* x    = (const float*)d_in[0];
  const float* n1_w = (const float*)d_in[1];  const float* n1_b = (const float*)d_in[2];
  const float* n2_w = (const float*)d_in[3];  const float* n2_b = (const float*)d_in[4];
  const float* n3_w = (const float*)d_in[5];  const float* n3_b = (const float*)d_in[6];
  const float* sn_w = (const float*)d_in[7];  const float* sn_b = (const float*)d_in[8];
  const float* tq_w = (const float*)d_in[9];  const float* tq_b = (const float*)d_in[10];
  const float* tk_w = (const float*)d_in[11]; const float* tk_b = (const float*)d_in[12];
  const float* tv_w = (const float*)d_in[13]; const float* tv_b = (const float*)d_in[14];
  const float* tp_w = (const float*)d_in[15]; const float* tp_b = (const float*)d_in[16];
  const float* sq_w = (const float*)d_in[17]; const float* sq_b = (const float*)d_in[18];
  const float* sk_w = (const float*)d_in[19]; const float* sk_b = (const float*)d_in[20];
  const float* sv_w = (const float*)d_in[21]; const float* sv_b = (const float*)d_in[22];
  const float* sp_w = (const float*)d_in[23]; const float* sp_b = (const float*)d_in[24];
  const float* sf_w = (const float*)d_in[25]; const float* sf_b = (const float*)d_in[26];
  const float* sc_w = (const float*)d_in[27]; const float* sc_b = (const float*)d_in[28];
  const float* m1_w = (const float*)d_in[29]; const float* m1_b = (const float*)d_in[30];
  const float* m2_w = (const float*)d_in[31]; const float* m2_b = (const float*)d_in[32];

  char* p = (char*)d_ws;
  auto alloc = [&](size_t bytes) { char* r = p; p += (bytes + 255) & ~(size_t)255; return r; };
  const long N = 16384;
  float* X0 = (float*)alloc(N * 128 * 4);
  u16* XN = (u16*)alloc(N * 128 * 2);
  u16* Qb = (u16*)alloc(N * 128 * 2);
  u16* Kb = (u16*)alloc(N * 128 * 2);
  u16* Vb = (u16*)alloc(N * 128 * 2);
  u16* Yb = (u16*)alloc(N * 128 * 2);
  u16* H  = (u16*)alloc(N * 512 * 2);
  u16* XC = (u16*)alloc(8 * 128 * 2);
  u16* XF = (u16*)alloc(1024 * 128 * 2);
  float* Kf = (float*)alloc(1032 * 128 * 4);
  float* Vf = (float*)alloc(1032 * 128 * 4);
  u16* Kh = (u16*)alloc(8 * 1032 * 16 * 2);
  u16* Vt = (u16*)alloc(8 * 16 * 1032 * 2);
  float* SPb = (float*)alloc(2L * N * 512 * 4);  // split-K partials (64 MB)
  u16* ZPb = (u16*)alloc(256);                    // zero page for masked gather rows
  u16* tq2 = (u16*)alloc(49152 * 2);  u16* tk2 = (u16*)alloc(49152 * 2);
  u16* tv2 = (u16*)alloc(49152 * 2);  u16* tp2 = (u16*)alloc(49152 * 2);
  u16* sq2 = (u16*)alloc(442368 * 2); u16* sk2 = (u16*)alloc(442368 * 2);
  u16* sv2 = (u16*)alloc(442368 * 2); u16* sp2 = (u16*)alloc(442368 * 2);
  u16* sf2 = (u16*)alloc(442368 * 2); u16* sc2 = (u16*)alloc(442368 * 2);
  u16* m12 = (u16*)alloc(5308416L * 2);
  u16* m22 = (u16*)alloc(5308416L * 2);

  k_zeropage<<<1, 128, 0, stream>>>(ZPb);

  auto rp = [&](const float* W, u16* Wb, int OC, int IC, int NT) {
    long tot = (long)OC * IC * NT;
    k_repack_bf<<<(int)((tot + 255) / 256), 256, 0, stream>>>(W, Wb, ilg(OC), ilg(IC), NT, tot);
  };
  rp(tq_w, tq2, 128, 128, 3);  rp(tk_w, tk2, 128, 128, 3);
  rp(tv_w, tv2, 128, 128, 3);  rp(tp_w, tp2, 128, 128, 3);
  rp(sq_w, sq2, 128, 128, 27); rp(sk_w, sk2, 128, 128, 27);
  rp(sv_w, sv2, 128, 128, 27); rp(sp_w, sp2, 128, 128, 27);
  rp(sf_w, sf2, 128, 128, 27); rp(sc_w, sc2, 128, 128, 27);
  rp(m1_w, m12, 512, 128, 81); rp(m2_w, m22, 128, 512, 81);

  // small convs (M not multiple of 128 or tiny grids)
  auto conv = [&](const u16* Xp, const u16* Wp, const float* Bp, void* Yp,
                  int M, int IC, int OC, int mode, int NT,
                  int Do, int Ho, int Wo, int Li, int Di, int Hi, int Wi,
                  int sL, int sD, int sH, int sW, int flags) {
    int lgWo = ilg(Wo), lgHo = ilg(Ho), lgDo = ilg(Do);
    int lgWi = ilg(Wi), lgHi = ilg(Hi), lgDi = ilg(Di);
    dim3 g((M + 63) / 64, OC / 64);
    k_conv_mfma<<<g, 256, 0, stream>>>(Xp, Wp, Bp, Yp, M, IC, OC, mode, NT,
                                       lgWo, lgHo, lgDo, lgWi, lgHi, lgDi,
                                       Li, Di, Hi, Wi, sL, sD, sH, sW, flags);
  };
  // big GEMMs on full 16384-token grid -> dbuf global_load_lds kernel (+ split-K)
  auto conv_gl = [&](const u16* Xp, const u16* Wp, const float* Bp, void* Yp,
                     int M, int IC, int OC, int mode, int NT, int nsplit, int flags) {
    dim3 g(M / 128, OC / 128, nsplit);
    k_conv_gl<<<g, 256, 0, stream>>>(Xp, Wp, Bp, Yp, SPb, ZPb, M, IC, OC, mode, NT, nsplit,
                                     4, 4, 4, 4, 4, 4, 4, 16, 16, 16, 1, 1, 1, 1, flags);
    if (nsplit > 1) {
      long MOC = (long)M * OC;
      k_combine<<<(int)((MOC + 255) / 256), 256, 0, stream>>>(SPb, Bp, Yp, MOC, ilg(OC),
                                                              nsplit, flags);
    }
  };

  k_transpose_in<<<8192, 256, 0, stream>>>(x, X0);

  // ---- TLG branch ----
  k_ln_f2b<<<4096, 256, 0, stream>>>(X0, n1_w, n1_b, XN, 16384);
  conv_gl(XN, tq2, tq_b, Qb, 16384, 128, 128, 0, 3, 3, 4);
  conv_gl(XN, tk2, tk_b, Kb, 16384, 128, 128, 0, 3, 3, 4);
  conv_gl(XN, tv2, tv_b, Vb, 16384, 128, 128, 0, 3, 3, 4);
  k_tlg_attn<<<4096, 256, 0, stream>>>(Qb, Kb, Vb, Yb);
  conv_gl(Yb, tp2, tp_b, X0, 16384, 128, 128, 0, 3, 3, 1);

  // ---- SLG branch ----
  k_ln_f2b<<<4096, 256, 0, stream>>>(X0, n2_w, n2_b, XN, 16384);
  conv_gl(XN, sq2, sq_b, Qb, 16384, 128, 128, 1, 27, 7, 4);
  conv(XN, sc2, sc_b, XC, 8,    128, 128, 1, 27, 2, 2, 2,   4, 16, 16, 16, 4, 8, 8, 8, 4);
  conv(XN, sf2, sf_b, XF, 1024, 128, 128, 1, 27, 8, 8, 8,   4, 16, 16, 16, 2, 2, 2, 2, 4);
  conv(XC, sk2, sk_b, Kf,            8,    128, 128, 1, 27, 2, 2, 2, 1, 2, 2, 2, 1, 1, 1, 1, 0);
  conv(XF, sk2, sk_b, Kf + 8 * 128,  1024, 128, 128, 1, 27, 8, 8, 8, 2, 8, 8, 8, 1, 1, 1, 1, 0);
  conv(XC, sv2, sv_b, Vf,            8,    128, 128, 1, 27, 2, 2, 2, 1, 2, 2, 2, 1, 1, 1, 1, 0);
  conv(XF, sv2, sv_b, Vf + 8 * 128,  1024, 128, 128, 1, 27, 8, 8, 8, 2, 8, 8, 8, 1, 1, 1, 1, 0);
  k_ln_f2b<<<258, 256, 0, stream>>>(Kf, sn_w, sn_b, Kb, 1032);
  k_ln_f2b<<<258, 256, 0, stream>>>(Vf, sn_w, sn_b, Vb, 1032);
  k_pack_kh<<<516, 256, 0, stream>>>(Kb, Kh);
  k_pack_vt<<<516, 256, 0, stream>>>(Vb, Vt);
  k_slg_flash<<<2048, 256, 0, stream>>>(Qb, Kh, Vt, Yb);
  conv_gl(Yb, sp2, sp_b, X0, 16384, 128, 128, 1, 27, 7, 1);

  // ---- MLP branch ----
  k_ln_f2b<<<4096, 256, 0, stream>>>(X0, n3_w, n3_b, XN, 16384);
  conv_gl(XN, m12, m1_b, H, 16384, 128, 512, 2, 81, 2, 6);
  conv_gl(H, m22, m2_b, X0, 16384, 512, 128, 2, 81, 8, 1);

  k_transpose_out<<<8192, 256, 0, stream>>>(X0, (float*)d_out);
}

// Round 7
// 1213.137 us; speedup vs baseline: 1.1441x; 1.1441x over previous
//
#include <hip/hip_runtime.h>

typedef unsigned short u16;
typedef __attribute__((ext_vector_type(8))) short bf16x8;
typedef __attribute__((ext_vector_type(4))) float f32x4;

#define PITCH 40   // small-conv kernel LDS pitch (shorts)

__device__ __forceinline__ u16 f2bf(float f) {
  union { float f; unsigned u; } v; v.f = f;
  unsigned r = v.u + 0x7fffu + ((v.u >> 16) & 1u);
  return (u16)(r >> 16);
}
__device__ __forceinline__ float bf2f(u16 h) {
  union { unsigned u; float f; } v; v.u = ((unsigned)h) << 16;
  return v.f;
}
__device__ __forceinline__ float4 load4bf(const u16* p) {
  ushort4 h = *(const ushort4*)p;
  return make_float4(bf2f(h.x), bf2f(h.y), bf2f(h.z), bf2f(h.w));
}
// async global->LDS, 16B per lane; LDS dest = wave-uniform base + lane*16
__device__ __forceinline__ void gll16(const u16* g, u16* l) {
  __builtin_amdgcn_global_load_lds(
      (const __attribute__((address_space(1))) unsigned int*)g,
      (__attribute__((address_space(3))) unsigned int*)l, 16, 0, 0);
}

// ---------------- tiled transpose (l,c,s) -> token-major [(l,s), c] fp32 ----------------
__global__ __launch_bounds__(256) void k_tin(const float* __restrict__ x,
                                             float* __restrict__ xt) {
  __shared__ float t[32][33];
  int s0 = blockIdx.x * 32, c0 = blockIdx.y * 32, l = blockIdx.z;
  int r = threadIdx.x >> 3, q4 = (threadIdx.x & 7) * 4;
  float4 v = *(const float4*)(x + ((long)(l * 128 + c0 + r) << 12) + s0 + q4);
  t[r][q4] = v.x; t[r][q4 + 1] = v.y; t[r][q4 + 2] = v.z; t[r][q4 + 3] = v.w;
  __syncthreads();
  float4 o = {t[q4][r], t[q4 + 1][r], t[q4 + 2][r], t[q4 + 3][r]};
  *(float4*)(xt + ((long)(l * 4096 + s0 + r) << 7) + c0 + q4) = o;
}

__global__ __launch_bounds__(256) void k_tout(const float* __restrict__ xt,
                                              float* __restrict__ out) {
  __shared__ float t[32][33];
  int s0 = blockIdx.x * 32, c0 = blockIdx.y * 32, l = blockIdx.z;
  int r = threadIdx.x >> 3, q4 = (threadIdx.x & 7) * 4;
  float4 v = *(const float4*)(xt + ((long)(l * 4096 + s0 + r) << 7) + c0 + q4);
  t[r][q4] = v.x; t[r][q4 + 1] = v.y; t[r][q4 + 2] = v.z; t[r][q4 + 3] = v.w;
  __syncthreads();
  float4 o = {t[q4][r], t[q4 + 1][r], t[q4 + 2][r], t[q4 + 3][r]};
  *(float4*)(out + ((long)(l * 128 + c0 + r) << 12) + s0 + q4) = o;
}

__global__ __launch_bounds__(128) void k_zeropage(u16* __restrict__ zp) {
  zp[threadIdx.x] = 0;
}

// ---------------- layernorm fp32 in -> bf16 out, one wave per row ----------------
__global__ __launch_bounds__(256) void k_ln_f2b(const float* __restrict__ X,
                                                const float* __restrict__ g,
                                                const float* __restrict__ b,
                                                u16* __restrict__ Y, int M) {
  int n = blockIdx.x * 4 + (threadIdx.x >> 6);
  if (n >= M) return;
  int lane = threadIdx.x & 63;
  const float* row = X + (long)n * 128;
  float2 v = *(const float2*)(row + lane * 2);
  float s = v.x + v.y;
#pragma unroll
  for (int o = 32; o > 0; o >>= 1) s += __shfl_xor(s, o);
  float mu = s * (1.0f / 128.0f);
  float dx = v.x - mu, dy = v.y - mu;
  float q = dx * dx + dy * dy;
#pragma unroll
  for (int o = 32; o > 0; o >>= 1) q += __shfl_xor(q, o);
  float rs = rsqrtf(q * (1.0f / 128.0f) + 1e-5f);
  float2 gv = *(const float2*)(g + lane * 2);
  float2 bv = *(const float2*)(b + lane * 2);
  ushort2 o2;
  o2.x = f2bf(dx * rs * gv.x + bv.x);
  o2.y = f2bf(dy * rs * gv.y + bv.y);
  *(ushort2*)(Y + (long)n * 128 + lane * 2) = o2;
}

// ---------------- coalesced weight repack: W[oc][ic][t] fp32 -> Wb[t][oc][ic] bf16 ----------
// one block per (oc, 128-ic chunk); coalesced read -> LDS -> transposed write
__global__ __launch_bounds__(256) void k_repack2(const float* __restrict__ W,
                                                 u16* __restrict__ Wb,
                                                 int OC, int IC, int NT) {
  __shared__ float ws[128 * 81];
  int oc = blockIdx.x, ic0 = blockIdx.y * 128;
  const float* src = W + ((long)oc * IC + ic0) * NT;
  int n = 128 * NT;
  for (int i = threadIdx.x; i < n; i += 256) ws[i] = src[i];
  __syncthreads();
  u16* dst = Wb + (long)oc * IC + ic0;
  long tstep = (long)OC * IC;
  for (int idx = threadIdx.x; idx < n; idx += 256) {
    int t = idx >> 7, i = idx & 127;
    dst[(long)t * tstep + i] = f2bf(ws[i * NT + t]);  // stride NT odd -> conflict-free
  }
}

// ---------------- small conv-as-gather-GEMM (64 x 64 tile) for small M ----------------
// flags: 1=ACC into fp32 Y, 2=RELU, 4=bf16 out (else fp32 out)
__global__ __launch_bounds__(256) void k_conv_mfma(
    const u16* __restrict__ X, const u16* __restrict__ W3,
    const float* __restrict__ bias, void* __restrict__ Yv,
    int M, int IC, int OC, int mode, int NT,
    int lgWo, int lgHo, int lgDo,
    int lgWi, int lgHi, int lgDi,
    int Li, int Di, int Hi, int Wi,
    int sL, int sD, int sH, int sW, int flags) {
  __shared__ u16 As[64 * PITCH];
  __shared__ u16 Bs[64 * PITCH];
  int tid = threadIdx.x;
  int wave = tid >> 6, lane = tid & 63;
  int quad = lane >> 4, l15 = lane & 15;
  int m0 = blockIdx.x * 64;
  int oc0 = blockIdx.y * 64;

  int srl = tid >> 2;
  int sao = (tid & 3) * 8;
  int sboc = tid >> 2, sbo = (tid & 3) * 8;

  int sm = m0 + srl;
  bool mv = sm < M;
  int w = sm & ((1 << lgWo) - 1);
  int h = (sm >> lgWo) & ((1 << lgHo) - 1);
  int d = (sm >> (lgWo + lgHo)) & ((1 << lgDo) - 1);
  int l = sm >> (lgWo + lgHo + lgDo);

  int c0 = 0, c1 = 0, c2 = 0, c3 = 0;
  auto comp_nb = [&]() -> long {
    if (!mv) return -1;
    int li, di, hi, wi; bool ok;
    if (mode == 0) {
      int dl = c0 - 1;
      int ll = (l & 1) + dl;
      ok = (ll >= 0 && ll < 2);
      li = l + dl; di = d; hi = h; wi = w;
    } else if (mode == 1) {
      li = l * sL; di = d * sD + c2 - 1; hi = h * sH + c1 - 1; wi = w * sW + c0 - 1;
      ok = ((unsigned)di < (unsigned)Di) && ((unsigned)hi < (unsigned)Hi) &&
           ((unsigned)wi < (unsigned)Wi);
    } else {
      li = l + c3 - 1; di = d + c2 - 1; hi = h + c1 - 1; wi = w + c0 - 1;
      ok = ((unsigned)li < (unsigned)Li) && ((unsigned)di < (unsigned)Di) &&
           ((unsigned)hi < (unsigned)Hi) && ((unsigned)wi < (unsigned)Wi);
    }
    if (!ok) return -1;
    return ((((long)((li << lgDi) + di) << lgHi) + hi) << lgWi) + wi;
  };

  long nb = comp_nb();
  const u16* wt = W3 + (long)(oc0 + sboc) * IC + sbo;
  long wstep = (long)OC * IC;
  int kmask = (IC >> 5) - 1;
  int total = NT * (IC >> 5);

  const bf16x8 Z = {0, 0, 0, 0, 0, 0, 0, 0};
  bf16x8 ra0 = Z, rb;
  if (nb >= 0) ra0 = *(const bf16x8*)(X + nb * IC + sao);
  rb = *(const bf16x8*)wt;

  f32x4 acc[4];
#pragma unroll
  for (int j = 0; j < 4; ++j) acc[j] = {0.f, 0.f, 0.f, 0.f};

  int wrow = wave * 16;

  for (int ks = 0; ks < total; ++ks) {
    __syncthreads();
    *(bf16x8*)&As[srl * PITCH + sao] = ra0;
    *(bf16x8*)&Bs[sboc * PITCH + sbo] = rb;
    __syncthreads();
    int ksn = ks + 1;
    if (ksn < total) {
      int k0n = (ksn & kmask) << 5;
      if ((ksn & kmask) == 0) {
        wt += wstep;
        if (++c0 == 3) { c0 = 0; if (++c1 == 3) { c1 = 0; if (++c2 == 3) { c2 = 0; ++c3; } } }
        nb = comp_nb();
      }
      ra0 = Z;
      if (nb >= 0) ra0 = *(const bf16x8*)(X + nb * IC + k0n + sao);
      rb = *(const bf16x8*)(wt + k0n);
    }
    bf16x8 a0 = *(const bf16x8*)&As[(wrow + l15) * PITCH + quad * 8];
#pragma unroll
    for (int j = 0; j < 4; ++j) {
      bf16x8 b = *(const bf16x8*)&Bs[(j * 16 + l15) * PITCH + quad * 8];
      acc[j] = __builtin_amdgcn_mfma_f32_16x16x32_bf16(a0, b, acc[j], 0, 0, 0);
    }
  }

  int col = oc0 + l15;
#pragma unroll
  for (int j = 0; j < 4; ++j) {
    float bj = bias[col + j * 16];
    int rbase = m0 + wrow + quad * 4;
#pragma unroll
    for (int r = 0; r < 4; ++r) {
      int row = rbase + r;
      if (row >= M) continue;
      float v = acc[j][r] + bj;
      if (flags & 2) v = fmaxf(v, 0.f);
      long off = (long)row * OC + col + j * 16;
      if (flags & 4) ((u16*)Yv)[off] = f2bf(v);
      else if (flags & 1) ((float*)Yv)[off] += v;
      else ((float*)Yv)[off] = v;
    }
  }
}

// ---------------- big conv-GEMM: 128x128 tile, BK=64, single-buffer global_load_lds ----------
// LDS [row][64 shorts] (8x16B chunks/row); chunk swizzle: physical = (logical + (row>>1)) & 7.
// 32 MFMA per barrier-drain (2x the BK=32 version). Invalid gather rows read zero page.
// NSPLIT>1 -> raw fp32 partials into SP. flags (NSPLIT==1): 1=ACC fp32, 2=RELU, 4=bf16 out
__global__ __launch_bounds__(256, 4) void k_conv_gl(
    const u16* __restrict__ X, const u16* __restrict__ W3,
    const float* __restrict__ bias, void* __restrict__ Yv, float* __restrict__ SP,
    const u16* __restrict__ ZP,
    int M, int IC, int OC, int mode, int NT, int NSPLIT,
    int lgWo, int lgHo, int lgDo,
    int lgWi, int lgHi, int lgDi,
    int Li, int Di, int Hi, int Wi,
    int sL, int sD, int sH, int sW, int flags) {
  __shared__ __align__(16) u16 As[128 * 64];
  __shared__ __align__(16) u16 Bs[128 * 64];
  int tid = threadIdx.x;
  int wave = tid >> 6, lane = tid & 63;
  int quad = lane >> 4, l15 = lane & 15;
  int m0 = blockIdx.x * 128, oc0 = blockIdx.y * 128;
  int mi = wave & 1, ni = wave >> 1;

  // staging: thread covers 4 A-rows and 4 B-rows (one per issue q)
  int rp[4], cA[4], sm[4];
#pragma unroll
  for (int q = 0; q < 4; ++q) {
    rp[q] = wave * 32 + q * 8 + (lane >> 3);
    cA[q] = ((lane & 7) - (rp[q] >> 1)) & 7;   // logical chunk stored at this slot
    sm[q] = m0 + rp[q];
  }

  int tap_per = (NT + NSPLIT - 1) / NSPLIT;
  int t0 = blockIdx.z * tap_per;
  int t1 = min(NT, t0 + tap_per);
  int kc = IC >> 6;                // 64-ch chunks
  int total = (t1 - t0) * kc;

  int c0 = t0 % 3, c1 = (t0 / 3) % 3, c2 = (t0 / 9) % 3, c3 = t0 / 27;
  auto comp_nb = [&](int smv) -> int {
    if (smv >= M) return -1;
    int w = smv & ((1 << lgWo) - 1);
    int h = (smv >> lgWo) & ((1 << lgHo) - 1);
    int d = (smv >> (lgWo + lgHo)) & ((1 << lgDo) - 1);
    int l = smv >> (lgWo + lgHo + lgDo);
    int li, di, hi, wi; bool ok;
    if (mode == 0) {
      int dl = c0 - 1;
      int ll = (l & 1) + dl;
      ok = (ll >= 0 && ll < 2);
      li = l + dl; di = d; hi = h; wi = w;
    } else if (mode == 1) {
      li = l * sL; di = d * sD + c2 - 1; hi = h * sH + c1 - 1; wi = w * sW + c0 - 1;
      ok = ((unsigned)di < (unsigned)Di) && ((unsigned)hi < (unsigned)Hi) &&
           ((unsigned)wi < (unsigned)Wi);
    } else {
      li = l + c3 - 1; di = d + c2 - 1; hi = h + c1 - 1; wi = w + c0 - 1;
      ok = ((unsigned)li < (unsigned)Li) && ((unsigned)di < (unsigned)Di) &&
           ((unsigned)hi < (unsigned)Hi) && ((unsigned)wi < (unsigned)Wi);
    }
    if (!ok) return -1;
    return (((li << lgDi) + di) << lgHi | hi) << lgWi | wi;
  };

  int nb[4];
#pragma unroll
  for (int q = 0; q < 4; ++q) nb[q] = comp_nb(sm[q]);
  long wstep = (long)OC * IC;
  const u16* wbase = W3 + (long)t0 * wstep + (long)oc0 * IC;

  f32x4 acc[4][4];
#pragma unroll
  for (int i = 0; i < 4; ++i)
#pragma unroll
    for (int j = 0; j < 4; ++j) acc[i][j] = {0.f, 0.f, 0.f, 0.f};

  int kk = 0;
  for (int ks = 0; ks < total; ++ks) {
    if (kk == kc) {
      kk = 0;
      if (++c0 == 3) { c0 = 0; if (++c1 == 3) { c1 = 0; if (++c2 == 3) { c2 = 0; ++c3; } } }
#pragma unroll
      for (int q = 0; q < 4; ++q) nb[q] = comp_nb(sm[q]);
      wbase += wstep;
    }
    int k0 = kk << 6;
    ++kk;
    __syncthreads();  // previous tile's ds_reads done
#pragma unroll
    for (int q = 0; q < 4; ++q) {
      const u16* a = (nb[q] >= 0) ? X + (long)nb[q] * IC + k0 + cA[q] * 8 : ZP;
      gll16(a, &As[(wave * 4 + q) * 512]);
    }
#pragma unroll
    for (int q = 0; q < 4; ++q) {
      const u16* bsrc = wbase + (long)rp[q] * IC + k0 + cA[q] * 8;
      gll16(bsrc, &Bs[(wave * 4 + q) * 512]);
    }
    __syncthreads();  // drains vmcnt(0): tile ready
#pragma unroll
    for (int ksub = 0; ksub < 2; ++ksub) {
      bf16x8 af[4], bf[4];
#pragma unroll
      for (int i = 0; i < 4; ++i) {
        int row = mi * 64 + i * 16 + l15;
        int pa = ((ksub * 4 + quad) + (row >> 1)) & 7;
        af[i] = *(const bf16x8*)&As[row * 64 + pa * 8];
      }
#pragma unroll
      for (int j = 0; j < 4; ++j) {
        int row = ni * 64 + j * 16 + l15;
        int pb = ((ksub * 4 + quad) + (row >> 1)) & 7;
        bf[j] = *(const bf16x8*)&Bs[row * 64 + pb * 8];
      }
#pragma unroll
      for (int i = 0; i < 4; ++i)
#pragma unroll
        for (int j = 0; j < 4; ++j)
          acc[i][j] = __builtin_amdgcn_mfma_f32_16x16x32_bf16(af[i], bf[j], acc[i][j], 0, 0, 0);
    }
  }

  // epilogue: C/D layout col=l15, row=quad*4+r
  if (NSPLIT > 1) {
    float* out = SP + (long)blockIdx.z * M * OC;
#pragma unroll
    for (int j = 0; j < 4; ++j) {
      int c = oc0 + ni * 64 + j * 16 + l15;
#pragma unroll
      for (int i = 0; i < 4; ++i) {
        int rbase = m0 + mi * 64 + i * 16 + quad * 4;
#pragma unroll
        for (int r = 0; r < 4; ++r) {
          int row = rbase + r;
          if (row < M) out[(long)row * OC + c] = acc[i][j][r];
        }
      }
    }
  } else {
#pragma unroll
    for (int j = 0; j < 4; ++j) {
      int c = oc0 + ni * 64 + j * 16 + l15;
      float bj = bias[c];
#pragma unroll
      for (int i = 0; i < 4; ++i) {
        int rbase = m0 + mi * 64 + i * 16 + quad * 4;
#pragma unroll
        for (int r = 0; r < 4; ++r) {
          int row = rbase + r;
          if (row >= M) continue;
          float v = acc[i][j][r] + bj;
          if (flags & 2) v = fmaxf(v, 0.f);
          long off = (long)row * OC + c;
          if (flags & 4) ((u16*)Yv)[off] = f2bf(v);
          else if (flags & 1) ((float*)Yv)[off] += v;
          else ((float*)Yv)[off] = v;
        }
      }
    }
  }
}

// ---------------- combine split-K partials: out = (sum_s SP[s]) + bias ----------------
__global__ __launch_bounds__(256) void k_combine(const float* __restrict__ SP,
                                                 const float* __restrict__ bias,
                                                 void* __restrict__ out,
                                                 long MOC, int lgOC, int nsplit, int flags) {
  long idx = (long)blockIdx.x * 256 + threadIdx.x;
  if (idx >= MOC) return;
  float v = bias[idx & ((1 << lgOC) - 1)];
  for (int s = 0; s < nsplit; ++s) v += SP[s * MOC + idx];
  if (flags & 2) v = fmaxf(v, 0.f);
  if (flags & 4) ((u16*)out)[idx] = f2bf(v);
  else if (flags & 1) ((float*)out)[idx] += v;
  else ((float*)out)[idx] = v;
}

// ---------------- TLG windowed cross attention: 8q x 8k per (window, head), bf16 ----------------
__global__ __launch_bounds__(256) void k_tlg_attn(const u16* __restrict__ Q,
                                                  const u16* __restrict__ K,
                                                  const u16* __restrict__ V,
                                                  u16* __restrict__ Y) {
  int gw = blockIdx.x * 4 + (threadIdx.x >> 6);
  int lane = threadIdx.x & 63;
  int head = gw & 7;
  int win = gw >> 3;
  int wB = win & 7, hB = (win >> 3) & 7, dB = (win >> 6) & 7, l = win >> 9;
  int i = lane >> 3, j = lane & 7;
  int nq = (l << 12) | ((dB * 2 + (i >> 2)) << 8) | ((hB * 2 + ((i >> 1) & 1)) << 4) |
           (wB * 2 + (i & 1));
  int lk = l ^ 2;
  int nk = (lk << 12) | ((dB * 2 + (j >> 2)) << 8) | ((hB * 2 + ((j >> 1) & 1)) << 4) |
           (wB * 2 + (j & 1));
  int hoff = head * 16;
  const u16* qp = Q + (long)nq * 128 + hoff;
  const u16* kp = K + (long)nk * 128 + hoff;
  float s = 0.f;
#pragma unroll
  for (int t = 0; t < 16; t += 4) {
    float4 a = load4bf(qp + t);
    float4 b = load4bf(kp + t);
    s += a.x * b.x + a.y * b.y + a.z * b.z + a.w * b.w;
  }
  s *= 0.25f;
  float mx = s;
#pragma unroll
  for (int o = 1; o < 8; o <<= 1) mx = fmaxf(mx, __shfl_xor(mx, o));
  float e = __expf(s - mx);
  float sum = e;
#pragma unroll
  for (int o = 1; o < 8; o <<= 1) sum += __shfl_xor(sum, o);
  float p = e / sum;
  const u16* vp = V + (long)nk * 128 + hoff;
  float y[16];
#pragma unroll
  for (int t = 0; t < 16; t += 4) {
    float4 vv = load4bf(vp + t);
    y[t] = p * vv.x; y[t + 1] = p * vv.y; y[t + 2] = p * vv.z; y[t + 3] = p * vv.w;
  }
#pragma unroll
  for (int o = 1; o < 8; o <<= 1) {
#pragma unroll
    for (int t = 0; t < 16; ++t) y[t] += __shfl_xor(y[t], o);
  }
  if (j == 0) {
    u16* yp = Y + (long)nq * 128 + hoff;
    u16 tmp[16];
#pragma unroll
    for (int t = 0; t < 16; ++t) tmp[t] = f2bf(y[t]);
    *(uint4*)(yp) = *(uint4*)tmp;
    *(uint4*)(yp + 8) = *(uint4*)(tmp + 8);
  }
}

// ---------------- SLG K/V repack for flash attn ----------------
__global__ __launch_bounds__(256) void k_pack_kh(const u16* __restrict__ Kin,
                                                 u16* __restrict__ Kh) {
  int idx = blockIdx.x * 256 + threadIdx.x;
  if (idx >= 8 * 1032 * 16) return;
  int d = idx & 15;
  int r = idx >> 4;
  int k = r % 1032, h = r / 1032;
  Kh[idx] = Kin[k * 128 + h * 16 + d];
}
__global__ __launch_bounds__(256) void k_pack_vt(const u16* __restrict__ Vin,
                                                 u16* __restrict__ Vt) {
  int idx = blockIdx.x * 256 + threadIdx.x;
  if (idx >= 8 * 16 * 1032) return;
  int k = idx % 1032;
  int r = idx / 1032;
  int d = r & 15, h = r >> 4;
  Vt[idx] = Vin[k * 128 + h * 16 + d];
}

// ---------------- SLG MFMA flash attention ----------------
__global__ __launch_bounds__(256) void k_slg_flash(const u16* __restrict__ Q,
                                                   const u16* __restrict__ Kh,
                                                   const u16* __restrict__ Vt,
                                                   u16* __restrict__ Y) {
  constexpr int NK = 1032;
  constexpr int NTILE = 17;
  __shared__ __align__(16) u16 Ks[64 * 24];
  __shared__ __align__(16) u16 Vs[16 * 72];
  __shared__ __align__(16) u16 Ps[4][16 * 72];
  int tid = threadIdx.x;
  int wave = tid >> 6, lane = tid & 63;
  int quad = lane >> 4, l15 = lane & 15;
  int h = blockIdx.x & 7;
  int q0 = (blockIdx.x >> 3) * 64 + wave * 16;

  const bf16x8 Zb = {0, 0, 0, 0, 0, 0, 0, 0};
  bf16x8 qf = Zb;
  if (quad < 2) qf = *(const bf16x8*)(Q + (long)(q0 + l15) * 128 + h * 16 + quad * 8);

  const u16* Kbase = Kh + (long)h * NK * 16;
  const u16* Vbase = Vt + (long)h * 16 * NK;

  float mrow[4], lrow[4];
  f32x4 oacc = {0.f, 0.f, 0.f, 0.f};
#pragma unroll
  for (int r = 0; r < 4; ++r) { mrow[r] = -1e30f; lrow[r] = 0.f; }

  int skey = tid >> 2, sch = (tid & 3) * 4;
  int svd = tid >> 4, svc = (tid & 15) * 4;

  for (int t = 0; t < NTILE; ++t) {
    int k0 = t * 64;
    __syncthreads();
    {
      short4 v = {0, 0, 0, 0};
      int key = k0 + skey;
      if (key < NK) v = *(const short4*)(Kbase + key * 16 + sch);
      *(short4*)&Ks[skey * 24 + sch] = v;
    }
    {
      short4 v = {0, 0, 0, 0};
      int colb = k0 + svc;
      if (colb < NK) v = *(const short4*)(Vbase + svd * NK + colb);
      *(short4*)&Vs[svd * 72 + svc] = v;
    }
    __syncthreads();

    f32x4 s[4];
#pragma unroll
    for (int sub = 0; sub < 4; ++sub) {
      bf16x8 b = Zb;
      if (quad < 2) b = *(const bf16x8*)&Ks[(sub * 16 + l15) * 24 + quad * 8];
      f32x4 zero = {0.f, 0.f, 0.f, 0.f};
      s[sub] = __builtin_amdgcn_mfma_f32_16x16x32_bf16(qf, b, zero, 0, 0, 0);
    }
    float pv[4][4];
    float tmax[4] = {-1e30f, -1e30f, -1e30f, -1e30f};
#pragma unroll
    for (int sub = 0; sub < 4; ++sub) {
      int key = k0 + sub * 16 + l15;
      bool valid = key < NK;
#pragma unroll
      for (int r = 0; r < 4; ++r) {
        float sv = valid ? s[sub][r] * 0.25f : -1e30f;
        pv[sub][r] = sv;
        tmax[r] = fmaxf(tmax[r], sv);
      }
    }
#pragma unroll
    for (int o = 1; o < 16; o <<= 1)
#pragma unroll
      for (int r = 0; r < 4; ++r) tmax[r] = fmaxf(tmax[r], __shfl_xor(tmax[r], o));

    float al[4], tsum[4] = {0.f, 0.f, 0.f, 0.f};
#pragma unroll
    for (int r = 0; r < 4; ++r) {
      float mn = fmaxf(mrow[r], tmax[r]);
      al[r] = __expf(mrow[r] - mn);
      mrow[r] = mn;
    }
#pragma unroll
    for (int sub = 0; sub < 4; ++sub)
#pragma unroll
      for (int r = 0; r < 4; ++r) {
        float pe = __expf(pv[sub][r] - mrow[r]);
        tsum[r] += pe;
        Ps[wave][(quad * 4 + r) * 72 + sub * 16 + l15] = f2bf(pe);
      }
#pragma unroll
    for (int o = 1; o < 16; o <<= 1)
#pragma unroll
      for (int r = 0; r < 4; ++r) tsum[r] += __shfl_xor(tsum[r], o);
#pragma unroll
    for (int r = 0; r < 4; ++r) {
      lrow[r] = lrow[r] * al[r] + tsum[r];
      oacc[r] *= al[r];
    }
    bf16x8 pa0 = *(const bf16x8*)&Ps[wave][l15 * 72 + quad * 8];
    bf16x8 pa1 = *(const bf16x8*)&Ps[wave][l15 * 72 + 32 + quad * 8];
    bf16x8 vb0 = *(const bf16x8*)&Vs[l15 * 72 + quad * 8];
    bf16x8 vb1 = *(const bf16x8*)&Vs[l15 * 72 + 32 + quad * 8];
    oacc = __builtin_amdgcn_mfma_f32_16x16x32_bf16(pa0, vb0, oacc, 0, 0, 0);
    oacc = __builtin_amdgcn_mfma_f32_16x16x32_bf16(pa1, vb1, oacc, 0, 0, 0);
  }

#pragma unroll
  for (int r = 0; r < 4; ++r) {
    float inv = 1.0f / lrow[r];
    Y[(long)(q0 + quad * 4 + r) * 128 + h * 16 + l15] = f2bf(oacc[r] * inv);
  }
}

static inline int ilg(int v) { int r = 0; while ((1 << r) < v) ++r; return r; }

extern "C" void kernel_launch(void* const* d_in, const int* in_sizes, int n_in,
                              void* d_out, int out_size, void* d_ws, size_t ws_size,
                              hipStream_t stream) {
  (void)in_sizes; (void)n_in; (void)out_size; (void)ws_size;
  const float* x    = (const float*)d_in[0];
  const float* n1_w = (const float*)d_in[1];  const float* n1_b = (const float*)d_in[2];
  const float* n2_w = (const float*)d_in[3];  const float* n2_b = (const float*)d_in[4];
  const float* n3_w = (const float*)d_in[5];  const float* n3_b = (const float*)d_in[6];
  const float* sn_w = (const float*)d_in[7];  const float* sn_b = (const float*)d_in[8];
  const float* tq_w = (const float*)d_in[9];  const float* tq_b = (const float*)d_in[10];
  const float* tk_w = (const float*)d_in[11]; const float* tk_b = (const float*)d_in[12];
  const float* tv_w = (const float*)d_in[13]; const float* tv_b = (const float*)d_in[14];
  const float* tp_w = (const float*)d_in[15]; const float* tp_b = (const float*)d_in[16];
  const float* sq_w = (const float*)d_in[17]; const float* sq_b = (const float*)d_in[18];
  const float* sk_w = (const float*)d_in[19]; const float* sk_b = (const float*)d_in[20];
  const float* sv_w = (const float*)d_in[21]; const float* sv_b = (const float*)d_in[22];
  const float* sp_w = (const float*)d_in[23]; const float* sp_b = (const float*)d_in[24];
  const float* sf_w = (const float*)d_in[25]; const float* sf_b = (const float*)d_in[26];
  const float* sc_w = (const float*)d_in[27]; const float* sc_b = (const float*)d_in[28];
  const float* m1_w = (const float*)d_in[29]; const float* m1_b = (const float*)d_in[30];
  const float* m2_w = (const float*)d_in[31]; const float* m2_b = (const float*)d_in[32];

  char* p = (char*)d_ws;
  auto alloc = [&](size_t bytes) { char* r = p; p += (bytes + 255) & ~(size_t)255; return r; };
  const long N = 16384;
  float* X0 = (float*)alloc(N * 128 * 4);
  u16* XN = (u16*)alloc(N * 128 * 2);
  u16* Qb = (u16*)alloc(N * 128 * 2);
  u16* Kb = (u16*)alloc(N * 128 * 2);
  u16* Vb = (u16*)alloc(N * 128 * 2);
  u16* Yb = (u16*)alloc(N * 128 * 2);
  u16* H  = (u16*)alloc(N * 512 * 2);
  u16* XC = (u16*)alloc(8 * 128 * 2);
  u16* XF = (u16*)alloc(1024 * 128 * 2);
  float* Kf = (float*)alloc(1032 * 128 * 4);
  float* Vf = (float*)alloc(1032 * 128 * 4);
  u16* Kh = (u16*)alloc(8 * 1032 * 16 * 2);
  u16* Vt = (u16*)alloc(8 * 16 * 1032 * 2);
  float* SPb = (float*)alloc(2L * N * 512 * 4);  // split-K partials (64 MB)
  u16* ZPb = (u16*)alloc(256);                    // zero page for masked gather rows
  u16* tq2 = (u16*)alloc(49152 * 2);  u16* tk2 = (u16*)alloc(49152 * 2);
  u16* tv2 = (u16*)alloc(49152 * 2);  u16* tp2 = (u16*)alloc(49152 * 2);
  u16* sq2 = (u16*)alloc(442368 * 2); u16* sk2 = (u16*)alloc(442368 * 2);
  u16* sv2 = (u16*)alloc(442368 * 2); u16* sp2 = (u16*)alloc(442368 * 2);
  u16* sf2 = (u16*)alloc(442368 * 2); u16* sc2 = (u16*)alloc(442368 * 2);
  u16* m12 = (u16*)alloc(5308416L * 2);
  u16* m22 = (u16*)alloc(5308416L * 2);

  k_zeropage<<<1, 128, 0, stream>>>(ZPb);

  auto rp = [&](const float* W, u16* Wb, int OC, int IC, int NT) {
    dim3 g(OC, IC / 128);
    k_repack2<<<g, 256, 0, stream>>>(W, Wb, OC, IC, NT);
  };
  rp(tq_w, tq2, 128, 128, 3);  rp(tk_w, tk2, 128, 128, 3);
  rp(tv_w, tv2, 128, 128, 3);  rp(tp_w, tp2, 128, 128, 3);
  rp(sq_w, sq2, 128, 128, 27); rp(sk_w, sk2, 128, 128, 27);
  rp(sv_w, sv2, 128, 128, 27); rp(sp_w, sp2, 128, 128, 27);
  rp(sf_w, sf2, 128, 128, 27); rp(sc_w, sc2, 128, 128, 27);
  rp(m1_w, m12, 512, 128, 81); rp(m2_w, m22, 128, 512, 81);

  // small convs (M not multiple of 128 or tiny grids)
  auto conv = [&](const u16* Xp, const u16* Wp, const float* Bp, void* Yp,
                  int M, int IC, int OC, int mode, int NT,
                  int Do, int Ho, int Wo, int Li, int Di, int Hi, int Wi,
                  int sL, int sD, int sH, int sW, int flags) {
    int lgWo = ilg(Wo), lgHo = ilg(Ho), lgDo = ilg(Do);
    int lgWi = ilg(Wi), lgHi = ilg(Hi), lgDi = ilg(Di);
    dim3 g((M + 63) / 64, OC / 64);
    k_conv_mfma<<<g, 256, 0, stream>>>(Xp, Wp, Bp, Yp, M, IC, OC, mode, NT,
                                       lgWo, lgHo, lgDo, lgWi, lgHi, lgDi,
                                       Li, Di, Hi, Wi, sL, sD, sH, sW, flags);
  };
  // big GEMMs -> BK=64 single-buffer global_load_lds kernel (+ split-K)
  auto conv_gl = [&](const u16* Xp, const u16* Wp, const float* Bp, void* Yp,
                     int M, int IC, int OC, int mode, int NT, int nsplit, int flags) {
    dim3 g(M / 128, OC / 128, nsplit);
    k_conv_gl<<<g, 256, 0, stream>>>(Xp, Wp, Bp, Yp, SPb, ZPb, M, IC, OC, mode, NT, nsplit,
                                     4, 4, 4, 4, 4, 4, 4, 16, 16, 16, 1, 1, 1, 1, flags);
    if (nsplit > 1) {
      long MOC = (long)M * OC;
      k_combine<<<(int)((MOC + 255) / 256), 256, 0, stream>>>(SPb, Bp, Yp, MOC, ilg(OC),
                                                              nsplit, flags);
    }
  };

  k_tin<<<dim3(128, 4, 4), 256, 0, stream>>>(x, X0);

  // ---- TLG branch ----
  k_ln_f2b<<<4096, 256, 0, stream>>>(X0, n1_w, n1_b, XN, 16384);
  conv_gl(XN, tq2, tq_b, Qb, 16384, 128, 128, 0, 3, 3, 4);
  conv_gl(XN, tk2, tk_b, Kb, 16384, 128, 128, 0, 3, 3, 4);
  conv_gl(XN, tv2, tv_b, Vb, 16384, 128, 128, 0, 3, 3, 4);
  k_tlg_attn<<<4096, 256, 0, stream>>>(Qb, Kb, Vb, Yb);
  conv_gl(Yb, tp2, tp_b, X0, 16384, 128, 128, 0, 3, 3, 1);

  // ---- SLG branch ----
  k_ln_f2b<<<4096, 256, 0, stream>>>(X0, n2_w, n2_b, XN, 16384);
  conv_gl(XN, sq2, sq_b, Qb, 16384, 128, 128, 1, 27, 7, 4);
  conv(XN, sc2, sc_b, XC, 8,    128, 128, 1, 27, 2, 2, 2,   4, 16, 16, 16, 4, 8, 8, 8, 4);
  conv(XN, sf2, sf_b, XF, 1024, 128, 128, 1, 27, 8, 8, 8,   4, 16, 16, 16, 2, 2, 2, 2, 4);
  conv(XC, sk2, sk_b, Kf,            8,    128, 128, 1, 27, 2, 2, 2, 1, 2, 2, 2, 1, 1, 1, 1, 0);
  conv(XF, sk2, sk_b, Kf + 8 * 128,  1024, 128, 128, 1, 27, 8, 8, 8, 2, 8, 8, 8, 1, 1, 1, 1, 0);
  conv(XC, sv2, sv_b, Vf,            8,    128, 128, 1, 27, 2, 2, 2, 1, 2, 2, 2, 1, 1, 1, 1, 0);
  conv(XF, sv2, sv_b, Vf + 8 * 128,  1024, 128, 128, 1, 27, 8, 8, 8, 2, 8, 8, 8, 1, 1, 1, 1, 0);
  k_ln_f2b<<<258, 256, 0, stream>>>(Kf, sn_w, sn_b, Kb, 1032);
  k_ln_f2b<<<258, 256, 0, stream>>>(Vf, sn_w, sn_b, Vb, 1032);
  k_pack_kh<<<516, 256, 0, stream>>>(Kb, Kh);
  k_pack_vt<<<516, 256, 0, stream>>>(Vb, Vt);
  k_slg_flash<<<2048, 256, 0, stream>>>(Qb, Kh, Vt, Yb);
  conv_gl(Yb, sp2, sp_b, X0, 16384, 128, 128, 1, 27, 7, 1);

  // ---- MLP branch ----
  k_ln_f2b<<<4096, 256, 0, stream>>>(X0, n3_w, n3_b, XN, 16384);
  conv_gl(XN, m12, m1_b, H, 16384, 128, 512, 2, 81, 2, 6);
  conv_gl(H, m22, m2_b, X0, 16384, 512, 128, 2, 81, 8, 1);

  k_tout<<<dim3(128, 4, 4), 256, 0, stream>>>(X0, (float*)d_out);
}